// Round 4
// baseline (200.817 us; speedup 1.0000x reference)
//
#include <hip/hip_runtime.h>
#include <hip/hip_bf16.h>

#define HIDDEN 1024
#define NHEAD 16
#define NKV 4
#define HDIM 64
#define KVDIM 256
#define SEQ 2048
#define BATCH 2
#define NQKV 1536   // 1024 (Q) + 256 (K) + 256 (V)

typedef __attribute__((ext_vector_type(4)))  float f32x4;
typedef __attribute__((ext_vector_type(16))) float f32x16;
typedef __attribute__((ext_vector_type(8)))  short s16x8;
typedef __attribute__((ext_vector_type(4)))  short s16x4;

#if defined(__has_builtin)
#if __has_builtin(__builtin_amdgcn_exp2f)
#define EXP2F(x) __builtin_amdgcn_exp2f(x)
#else
#define EXP2F(x) exp2f(x)
#endif
#else
#define EXP2F(x) exp2f(x)
#endif

static __device__ __forceinline__ ushort f2bf(float f) {
    union { __hip_bfloat16 b; ushort u; } cv; cv.b = __float2bfloat16(f); return cv.u;
}
// pack two positive finite f32 into (lo,hi) bf16 pair, round-half-up
static __device__ __forceinline__ unsigned pack_rh2(float a, float b) {
    unsigned ua = __float_as_uint(a) + 0x8000u;
    unsigned ub = __float_as_uint(b) + 0x8000u;
    return (ua >> 16) | (ub & 0xFFFF0000u);
}
// async global->LDS, 16B per lane. LDS dest = wave-uniform base + lane*16.
static __device__ __forceinline__ void async16(const void* g, void* l) {
    __builtin_amdgcn_global_load_lds((__attribute__((address_space(1))) void*)g,
                                     (__attribute__((address_space(3))) void*)l, 16, 0, 0);
}

// ---------------------------------------------------------------------------
// Fused prep: grid [0,4096) = X fp32->bf16; [4096,4480) = Wq/Wk/Wv transpose;
// [4480,4736) = Wo transpose. One dispatch instead of three.
// ---------------------------------------------------------------------------
__global__ __launch_bounds__(256)
void prep(const float* __restrict__ X, ushort* __restrict__ Xb,
          const float* __restrict__ Wq, const float* __restrict__ Wk,
          const float* __restrict__ Wv, ushort* __restrict__ Tqkv,
          const float* __restrict__ Wo, ushort* __restrict__ Two)
{
    __shared__ float Tl[64][65];
    const int bid = blockIdx.x, tid = threadIdx.x;

    if (bid < 4096) {           // ---- cvt_x: 4096 blocks x 256 thr x float4
        int i = bid * 256 + tid;
        float4 v = ((const float4*)X)[i];
        ushort4 o;
        o.x = f2bf(v.x); o.y = f2bf(v.y); o.z = f2bf(v.z); o.w = f2bf(v.w);
        ((ushort4*)Xb)[i] = o;
        return;
    }

    const float* W; ushort* T; int N, n0, k0, roff;
    if (bid < 4096 + 384) {     // ---- wtrans_qkv (24 x 16)
        int wq = bid - 4096;
        int bx = wq % 24; k0 = (wq / 24) * 64;
        T = Tqkv;
        if (bx < 16)      { W = Wq; N = 1024; n0 = bx * 64;        roff = 0; }
        else if (bx < 20) { W = Wk; N = 256;  n0 = (bx - 16) * 64; roff = 1024; }
        else              { W = Wv; N = 256;  n0 = (bx - 20) * 64; roff = 1280; }
    } else {                    // ---- wtrans_one (Wo, 16 x 16)
        int wo = bid - 4480;
        int bx = wo % 16; k0 = (wo / 16) * 64;
        W = Wo; T = Two; N = 1024; n0 = bx * 64; roff = 0;
    }

#pragma unroll
    for (int it = 0; it < 4; it++) {
        int idx = tid + it * 256;
        int kk = idx >> 4, n4 = (idx & 15) * 4;
        float4 v = *(const float4*)(W + (size_t)(k0 + kk) * N + n0 + n4);
        Tl[kk][n4 + 0] = v.x; Tl[kk][n4 + 1] = v.y;
        Tl[kk][n4 + 2] = v.z; Tl[kk][n4 + 3] = v.w;
    }
    __syncthreads();
#pragma unroll
    for (int it = 0; it < 4; it++) {
        int idx = tid + it * 256;
        int n = idx >> 4, k4 = (idx & 15) * 4;
        ushort4 h4;
        h4.x = f2bf(Tl[k4 + 0][n]); h4.y = f2bf(Tl[k4 + 1][n]);
        h4.z = f2bf(Tl[k4 + 2][n]); h4.w = f2bf(Tl[k4 + 3][n]);
        *(ushort4*)(T + (size_t)(roff + n0 + n) * HIDDEN + k0 + k4) = h4;
    }
}

// ---------------------------------------------------------------------------
// Plain-bf16 MFMA GEMM (R0 geometry — measured best): C = A[M,K]@B^T[N,K]+bias.
// 64x128 tile (M x N), BK=32, 4 waves 2x2; per wave 2x4 grid of 16x16x32.
// Grids: gemm0 (12,64)=768 wgs ~3/CU; gemm1 (8,64)=512 wgs = 2/CU.
// Error analysis: QKV operand-rounding ~2.5e-3 on q~0.64 contracts via
// softmax-averaging to ~7e-5 in ctx; O-proj ~3.5e-5. Both << 1.07e-3.
// MODE 0: bf16 out (Q cols scaled 0.125*log2e). MODE 1: fp32 out.
// ---------------------------------------------------------------------------
template <int MODE>
__global__ __launch_bounds__(256)
void gemm_bf(const ushort* __restrict__ A, const ushort* __restrict__ Bt,
             const float* __restrict__ b0, const float* __restrict__ b1,
             const float* __restrict__ b2, void* __restrict__ Cout,
             int M, int N, int K)
{
    __shared__ __align__(16) ushort Ah[64 * 32];
    __shared__ __align__(16) ushort Bh[128 * 32];

    const int tid = threadIdx.x;
    const int lane = tid & 63, wv = tid >> 6;
    const int wr = wv >> 1, wc = wv & 1;
    const int m = lane & 15, c = lane >> 4;
    const int row0 = blockIdx.y * 64, col0 = blockIdx.x * 128;

    // A staging: 1 slot/thread (64 rows x 32 cols)
    const ushort* gA = A + (size_t)(row0 + (tid >> 2)) * K + (tid & 3) * 8;
    const int ldsA = tid * 8;
    // B staging: 2 slots/thread (128 rows x 32 cols)
    const ushort* gB[2]; int ldsB[2];
#pragma unroll
    for (int it = 0; it < 2; it++) {
        int idx = it * 256 + tid;
        gB[it] = Bt + (size_t)(col0 + (idx >> 2)) * K + (idx & 3) * 8;
        ldsB[it] = idx * 8;
    }

    f32x4 acc[2][4];
#pragma unroll
    for (int t = 0; t < 2; t++)
#pragma unroll
        for (int u = 0; u < 4; u++) acc[t][u] = (f32x4){0.f, 0.f, 0.f, 0.f};

    for (int k0 = 0; k0 < K; k0 += 32) {
        __syncthreads();
        async16(gA + k0, Ah + ldsA);
#pragma unroll
        for (int it = 0; it < 2; it++) async16(gB[it] + k0, Bh + ldsB[it]);
        __syncthreads();

        s16x8 ah[2], bh[4];
#pragma unroll
        for (int t = 0; t < 2; t++)
            ah[t] = *(const s16x8*)&Ah[(wr * 32 + t * 16 + m) * 32 + c * 8];
#pragma unroll
        for (int u = 0; u < 4; u++)
            bh[u] = *(const s16x8*)&Bh[(wc * 64 + u * 16 + m) * 32 + c * 8];
#pragma unroll
        for (int t = 0; t < 2; t++)
#pragma unroll
            for (int u = 0; u < 4; u++)
                acc[t][u] = __builtin_amdgcn_mfma_f32_16x16x32_bf16(ah[t], bh[u], acc[t][u], 0, 0, 0);
    }

    const int orow = row0 + wr * 32 + 4 * c;   // + 16t + r
    const int ocol = col0 + wc * 64 + m;       // + 16u
    if (MODE == 0) {
        ushort* Cb = (ushort*)Cout;
#pragma unroll
        for (int u = 0; u < 4; u++) {
            int n = ocol + 16 * u;
            float bias, scl;
            if (n < 1024)      { bias = b0[n];        scl = 0.18033688f; }  // 0.125*log2(e)
            else if (n < 1280) { bias = b1[n - 1024]; scl = 1.0f; }
            else               { bias = b2[n - 1280]; scl = 1.0f; }
#pragma unroll
            for (int t = 0; t < 2; t++)
#pragma unroll
                for (int r = 0; r < 4; r++)
                    Cb[(size_t)(orow + 16 * t + r) * N + n] = f2bf((acc[t][u][r] + bias) * scl);
        }
    } else {
        float* Cf = (float*)Cout;
#pragma unroll
        for (int u = 0; u < 4; u++) {
            int n = ocol + 16 * u;
            float bias = b0[n];
#pragma unroll
            for (int t = 0; t < 2; t++)
#pragma unroll
                for (int r = 0; r < 4; r++)
                    Cf[(size_t)(orow + 16 * t + r) * N + n] = acc[t][u][r] + bias;
        }
    }
}

// ---------------------------------------------------------------------------
// Pack K and V (bf16 cols of QKV) into fragment-major buffers (unchanged).
// ---------------------------------------------------------------------------
__global__ __launch_bounds__(256)
void kvpack(const ushort* __restrict__ QKV, ushort* __restrict__ Kf,
            ushort* __restrict__ Vf)
{
    __shared__ __align__(16) ushort Kt[64][72];
    __shared__ __align__(16) ushort Vt[64][72];
    const int kt = blockIdx.x, hk = blockIdx.y, b = blockIdx.z;
    const int tid = threadIdx.x;

#pragma unroll
    for (int it = 0; it < 2; it++) {
        int idx = tid + it * 256;
        int r = idx >> 3, c8 = (idx & 7) * 8;
        const ushort* src = QKV + (size_t)(b * SEQ + kt * 64 + r) * NQKV + hk * HDIM + c8;
        *(s16x8*)&Kt[r][c8] = *(const s16x8*)(src + 1024);
        *(s16x8*)&Vt[r][c8] = *(const s16x8*)(src + 1280);
    }
    __syncthreads();

#pragma unroll
    for (int it = 0; it < 2; it++) {
        int idx = tid + it * 256;
        int t32 = idx >> 8, kc = (idx >> 6) & 3, lane = idx & 63;
        int n32 = lane & 31, h5 = lane >> 5;
        s16x8 fr = *(const s16x8*)&Kt[t32 * 32 + n32][kc * 16 + h5 * 8];
        size_t flat = ((size_t)(((b * NKV + hk) * 64 + kt * 2 + t32) * 4 + kc) * 64 + lane) * 8;
        *(s16x8*)(Kf + flat) = fr;
    }
#pragma unroll
    for (int it = 0; it < 2; it++) {
        int idx = tid + it * 256;
        int kcdn = idx >> 6, lane = idx & 63;
        int kc = kcdn >> 1, dn = kcdn & 1;
        int n32 = lane & 31, h5 = lane >> 5;
        s16x8 fr;
#pragma unroll
        for (int j = 0; j < 8; j++)
            fr[j] = (short)Vt[kc * 16 + h5 * 8 + j][dn * 32 + n32];
        size_t flat = ((size_t)(((b * NKV + hk) * 32 + kt) * 8 + kc * 2 + dn) * 64 + lane) * 8;
        *(s16x8*)(Vf + flat) = fr;
    }
}

// ---------------------------------------------------------------------------
// Flash attention v7 (exact measured-best core: 80 VGPR, 61.4 us): S^T layout,
// stride-68 Ps, ones-MFMA l, depth-1 pipeline, single-plane bf16 ctx output.
// Post-R2/R3 note: setprio and V-reg-dbuf variants BOTH regressed this loop
// (96 VGPR, 70-77 us) — do not perturb the macro bodies or register budget.
// ---------------------------------------------------------------------------
__global__ __launch_bounds__(512, 2)
void attn_mfma7(const ushort* __restrict__ QKV, const ushort* __restrict__ Kf,
                const ushort* __restrict__ Vf, ushort* __restrict__ Chi)
{
    __shared__ __align__(16) ushort Ps[8][32][68];   // 34,816 B; merge bufs alias
    float* OLb = (float*)&Ps[0][0][0];               // [4][32][64] = 32,768 B
    float* LLb = (float*)((char*)&Ps[0][0][0] + 33024);  // [4][32]

    const int tid = threadIdx.x, w = tid >> 6, lane = tid & 63;
    const int g = w >> 2, ws_ = w & 3;               // q-group, kt-split index
    const int n32 = lane & 31, h5 = lane >> 5;
    const int h = blockIdx.y, b = blockIdx.z, hk = h >> 2;
    const int q0 = blockIdx.x * 64 + g * 32;

    // Q B-fragments (4 k-chunks of 16), hoisted
    const ushort* qrow = QKV + (size_t)(b * SEQ + q0 + n32) * NQKV + h * HDIM + h5 * 8;
    s16x8 aq[4];
#pragma unroll
    for (int kc = 0; kc < 4; kc++) aq[kc] = *(const s16x8*)(qrow + kc * 16);

    f32x16 accO[2], accl;
#pragma unroll
    for (int j = 0; j < 16; j++) { accO[0][j] = 0.f; accO[1][j] = 0.f; accl[j] = 0.f; }

    s16x8 ones;
#pragma unroll
    for (int j = 0; j < 8; j++) ones[j] = (short)0x3F80;   // bf16 1.0

    const ushort* kf0 = Kf + (size_t)(b * NKV + hk) * (64 * 4 * 64 * 8) + (size_t)lane * 8;
    const ushort* vf0 = Vf + (size_t)(b * NKV + hk) * (32 * 8 * 64 * 8) + (size_t)lane * 8;

    s16x8 kreg[8], vreg[8];

#define LOAD_K(kt_) do {                                                      \
    _Pragma("unroll")                                                         \
    for (int kn = 0; kn < 2; kn++)                                            \
        _Pragma("unroll")                                                     \
        for (int kc = 0; kc < 4; kc++)                                        \
            kreg[kn * 4 + kc] =                                               \
                *(const s16x8*)(kf0 + (size_t)(((kt_) * 2 + kn) * 4 + kc) * 512); \
} while (0)

#define LOAD_V(kt_) do {                                                      \
    _Pragma("unroll")                                                         \
    for (int kc = 0; kc < 4; kc++)                                            \
        _Pragma("unroll")                                                     \
        for (int dn = 0; dn < 2; dn++)                                        \
            vreg[kc * 2 + dn] =                                               \
                *(const s16x8*)(vf0 + (size_t)((kt_) * 8 + kc * 2 + dn) * 512); \
} while (0)

// S^T = K Q^T: lane owns q=n32; key(reg) = kn*32 + (reg&3) + 8*(reg>>2) + 4*h5.
// exp2 in log2 domain (log2e folded into Q), packed b64 stores.
#define QK_EXP_STORE() do {                                                   \
    _Pragma("unroll")                                                         \
    for (int kn = 0; kn < 2; kn++) {                                          \
        f32x16 S;                                                             \
        _Pragma("unroll")                                                     \
        for (int j = 0; j < 16; j++) S[j] = 0.f;                              \
        _Pragma("unroll")                                                     \
        for (int kc = 0; kc < 4; kc++)                                        \
            S = __builtin_amdgcn_mfma_f32_32x32x16_bf16(kreg[kn * 4 + kc],    \
                    aq[kc], S, 0, 0, 0);                                      \
        float p[16];                                                          \
        _Pragma("unroll")                                                     \
        for (int reg = 0; reg < 16; reg++) p[reg] = EXP2F(S[reg]);            \
        _Pragma("unroll")                                                     \
        for (int t = 0; t < 4; t++) {                                         \
            uint2 pk;                                                         \
            pk.x = pack_rh2(p[4 * t + 0], p[4 * t + 1]);                      \
            pk.y = pack_rh2(p[4 * t + 2], p[4 * t + 3]);                      \
            *(uint2*)&Ps[w][n32][kn * 32 + 8 * t + 4 * h5] = pk;              \
        }                                                                     \
    }                                                                         \
} while (0)

#define PV_STEP() do {                                                        \
    s16x8 pa[4];                                                              \
    _Pragma("unroll")                                                         \
    for (int kc = 0; kc < 4; kc++) {                                          \
        s16x4 lo4 = *(const s16x4*)&Ps[w][n32][kc * 16 + h5 * 8];             \
        s16x4 hi4 = *(const s16x4*)&Ps[w][n32][kc * 16 + h5 * 8 + 4];         \
        pa[kc] = __builtin_shufflevector(lo4, hi4, 0, 1, 2, 3, 4, 5, 6, 7);   \
    }                                                                         \
    _Pragma("unroll")                                                         \
    for (int kc = 0; kc < 4; kc++) {                                          \
        accl = __builtin_amdgcn_mfma_f32_32x32x16_bf16(pa[kc], ones, accl, 0, 0, 0); \
        _Pragma("unroll")                                                     \
        for (int dn = 0; dn < 2; dn++)                                        \
            accO[dn] = __builtin_amdgcn_mfma_f32_32x32x16_bf16(pa[kc],        \
                           vreg[kc * 2 + dn], accO[dn], 0, 0, 0);             \
    }                                                                         \
} while (0)

    // prologue: first tile's scores
    LOAD_K(ws_);
    QK_EXP_STORE();

    for (int i = 1; i < 8; i++) {
        const int ktc = ws_ + 4 * i;
        LOAD_V(ktc - 4);     // V for previous tile (issued first: partial vm wait)
        LOAD_K(ktc);         // K for current tile
        PV_STEP();           // PV(prev): reads Ps BEFORE the writes below (in-order DS)
        QK_EXP_STORE();      // scores(cur) + overwrite Ps
    }

    // epilogue: last tile's PV
    LOAD_V(ws_ + 28);
    PV_STEP();

#undef LOAD_K
#undef LOAD_V
#undef QK_EXP_STORE
#undef PV_STEP

    __syncthreads();   // everyone done with Ps — safe to alias merge buffers

    const int qq = tid >> 4;          // 0..31
    const int d0 = (tid & 15) * 4;    // 0..60
#pragma unroll
    for (int phase = 0; phase < 2; phase++) {
        if (g == phase) {
#pragma unroll
            for (int reg = 0; reg < 16; reg++) {
                int q = (reg & 3) + 8 * (reg >> 2) + 4 * h5;
                OLb[(ws_ * 32 + q) * 64 + n32]      = accO[0][reg];
                OLb[(ws_ * 32 + q) * 64 + 32 + n32] = accO[1][reg];
                if (n32 == 0) LLb[ws_ * 32 + q] = accl[reg];
            }
        }
        __syncthreads();
        {
            float lsum = LLb[qq] + LLb[32 + qq] + LLb[64 + qq] + LLb[96 + qq];
            float inv = 1.f / lsum;
            ushort4 hs;
            float o0 = (OLb[(0 * 32 + qq) * 64 + d0 + 0] + OLb[(1 * 32 + qq) * 64 + d0 + 0] +
                        OLb[(2 * 32 + qq) * 64 + d0 + 0] + OLb[(3 * 32 + qq) * 64 + d0 + 0]) * inv;
            float o1 = (OLb[(0 * 32 + qq) * 64 + d0 + 1] + OLb[(1 * 32 + qq) * 64 + d0 + 1] +
                        OLb[(2 * 32 + qq) * 64 + d0 + 1] + OLb[(3 * 32 + qq) * 64 + d0 + 1]) * inv;
            float o2 = (OLb[(0 * 32 + qq) * 64 + d0 + 2] + OLb[(1 * 32 + qq) * 64 + d0 + 2] +
                        OLb[(2 * 32 + qq) * 64 + d0 + 2] + OLb[(3 * 32 + qq) * 64 + d0 + 2]) * inv;
            float o3 = (OLb[(0 * 32 + qq) * 64 + d0 + 3] + OLb[(1 * 32 + qq) * 64 + d0 + 3] +
                        OLb[(2 * 32 + qq) * 64 + d0 + 3] + OLb[(3 * 32 + qq) * 64 + d0 + 3]) * inv;
            hs.x = f2bf(o0); hs.y = f2bf(o1); hs.z = f2bf(o2); hs.w = f2bf(o3);
            size_t off = (size_t)(b * SEQ + blockIdx.x * 64 + phase * 32 + qq) * HIDDEN
                       + h * HDIM + d0;
            *(ushort4*)(Chi + off) = hs;
        }
        __syncthreads();   // before next phase overwrites merge buffers
    }
}

// ---------------------------------------------------------------------------
extern "C" void kernel_launch(void* const* d_in, const int* in_sizes, int n_in,
                              void* d_out, int out_size, void* d_ws, size_t ws_size,
                              hipStream_t stream)
{
    const float* X  = (const float*)d_in[0];
    const float* Wq = (const float*)d_in[1];
    const float* bq = (const float*)d_in[2];
    const float* Wk = (const float*)d_in[3];
    const float* bk = (const float*)d_in[4];
    const float* Wv = (const float*)d_in[5];
    const float* bv = (const float*)d_in[6];
    const float* Wo = (const float*)d_in[7];
    const float* bo = (const float*)d_in[8];
    float* out = (float*)d_out;

    const int M = BATCH * SEQ;  // 4096
    // ws layout (37 MB): Xb 8 | Ctx 8 | QKVb 12 | Wqkvt 3 | Wot 2 | Kf 2 | Vf 2
    char* ws = (char*)d_ws;
    ushort* Xb    = (ushort*)(ws);
    ushort* Ctx   = (ushort*)(ws + (8u  << 20));
    ushort* QKVb  = (ushort*)(ws + (16u << 20));
    ushort* Wqkvt = (ushort*)(ws + (28u << 20));
    ushort* Wot   = (ushort*)(ws + (31u << 20));
    ushort* Kf    = (ushort*)(ws + (33u << 20));
    ushort* Vf    = (ushort*)(ws + (35u << 20));

    prep<<<dim3(4736), 256, 0, stream>>>(X, Xb, Wq, Wk, Wv, Wqkvt, Wo, Wot);

    gemm_bf<0><<<dim3(NQKV / 128, M / 64), 256, 0, stream>>>(
        Xb, Wqkvt, bq, bk, bv, (void*)QKVb, M, NQKV, HIDDEN);

    kvpack<<<dim3(SEQ / 64, NKV, BATCH), 256, 0, stream>>>(QKVb, Kf, Vf);

    attn_mfma7<<<dim3(SEQ / 64, NHEAD, BATCH), 512, 0, stream>>>(QKVb, Kf, Vf, Ctx);

    gemm_bf<1><<<dim3(HIDDEN / 128, M / 64), 256, 0, stream>>>(
        Ctx, Wot, bo, nullptr, nullptr, (void*)out, M, HIDDEN, HIDDEN);
}

// Round 5
// 196.310 us; speedup vs baseline: 1.0230x; 1.0230x over previous
//
#include <hip/hip_runtime.h>
#include <hip/hip_bf16.h>

#define HIDDEN 1024
#define NHEAD 16
#define NKV 4
#define HDIM 64
#define KVDIM 256
#define SEQ 2048
#define BATCH 2
#define NQKV 1536   // 1024 (Q) + 256 (K) + 256 (V)

typedef __attribute__((ext_vector_type(4)))  float f32x4;
typedef __attribute__((ext_vector_type(16))) float f32x16;
typedef __attribute__((ext_vector_type(8)))  short s16x8;
typedef __attribute__((ext_vector_type(4)))  short s16x4;

#if defined(__has_builtin)
#if __has_builtin(__builtin_amdgcn_exp2f)
#define EXP2F(x) __builtin_amdgcn_exp2f(x)
#else
#define EXP2F(x) exp2f(x)
#endif
#else
#define EXP2F(x) exp2f(x)
#endif

static __device__ __forceinline__ ushort f2bf(float f) {
    union { __hip_bfloat16 b; ushort u; } cv; cv.b = __float2bfloat16(f); return cv.u;
}
// pack two positive finite f32 into (lo,hi) bf16 pair, round-half-up
static __device__ __forceinline__ unsigned pack_rh2(float a, float b) {
    unsigned ua = __float_as_uint(a) + 0x8000u;
    unsigned ub = __float_as_uint(b) + 0x8000u;
    return (ua >> 16) | (ub & 0xFFFF0000u);
}
// async global->LDS, 16B per lane. LDS dest = wave-uniform base + lane*16.
static __device__ __forceinline__ void async16(const void* g, void* l) {
    __builtin_amdgcn_global_load_lds((__attribute__((address_space(1))) void*)g,
                                     (__attribute__((address_space(3))) void*)l, 16, 0, 0);
}

// ---------------------------------------------------------------------------
// Fused prep: grid [0,4096) = X fp32->bf16; [4096,4480) = Wq/Wk/Wv transpose;
// [4480,4736) = Wo transpose. One dispatch instead of three.
// ---------------------------------------------------------------------------
__global__ __launch_bounds__(256)
void prep(const float* __restrict__ X, ushort* __restrict__ Xb,
          const float* __restrict__ Wq, const float* __restrict__ Wk,
          const float* __restrict__ Wv, ushort* __restrict__ Tqkv,
          const float* __restrict__ Wo, ushort* __restrict__ Two)
{
    __shared__ float Tl[64][65];
    const int bid = blockIdx.x, tid = threadIdx.x;

    if (bid < 4096) {           // ---- cvt_x: 4096 blocks x 256 thr x float4
        int i = bid * 256 + tid;
        float4 v = ((const float4*)X)[i];
        ushort4 o;
        o.x = f2bf(v.x); o.y = f2bf(v.y); o.z = f2bf(v.z); o.w = f2bf(v.w);
        ((ushort4*)Xb)[i] = o;
        return;
    }

    const float* W; ushort* T; int N, n0, k0, roff;
    if (bid < 4096 + 384) {     // ---- wtrans_qkv (24 x 16)
        int wq = bid - 4096;
        int bx = wq % 24; k0 = (wq / 24) * 64;
        T = Tqkv;
        if (bx < 16)      { W = Wq; N = 1024; n0 = bx * 64;        roff = 0; }
        else if (bx < 20) { W = Wk; N = 256;  n0 = (bx - 16) * 64; roff = 1024; }
        else              { W = Wv; N = 256;  n0 = (bx - 20) * 64; roff = 1280; }
    } else {                    // ---- wtrans_one (Wo, 16 x 16)
        int wo = bid - 4480;
        int bx = wo % 16; k0 = (wo / 16) * 64;
        W = Wo; T = Two; N = 1024; n0 = bx * 64; roff = 0;
    }

#pragma unroll
    for (int it = 0; it < 4; it++) {
        int idx = tid + it * 256;
        int kk = idx >> 4, n4 = (idx & 15) * 4;
        float4 v = *(const float4*)(W + (size_t)(k0 + kk) * N + n0 + n4);
        Tl[kk][n4 + 0] = v.x; Tl[kk][n4 + 1] = v.y;
        Tl[kk][n4 + 2] = v.z; Tl[kk][n4 + 3] = v.w;
    }
    __syncthreads();
#pragma unroll
    for (int it = 0; it < 4; it++) {
        int idx = tid + it * 256;
        int n = idx >> 4, k4 = (idx & 15) * 4;
        ushort4 h4;
        h4.x = f2bf(Tl[k4 + 0][n]); h4.y = f2bf(Tl[k4 + 1][n]);
        h4.z = f2bf(Tl[k4 + 2][n]); h4.w = f2bf(Tl[k4 + 3][n]);
        *(ushort4*)(T + (size_t)(roff + n0 + n) * HIDDEN + k0 + k4) = h4;
    }
}

// ---------------------------------------------------------------------------
// Plain-bf16 MFMA GEMM (R0 geometry — measured best): C = A[M,K]@B^T[N,K]+bias.
// 64x128 tile (M x N), BK=32, 4 waves 2x2; per wave 2x4 grid of 16x16x32.
// Grids: gemm0 (12,64)=768 wgs ~3/CU; gemm1 (8,64)=512 wgs = 2/CU.
// Error analysis: QKV operand-rounding ~2.5e-3 on q~0.64 contracts via
// softmax-averaging to ~7e-5 in ctx; O-proj ~3.5e-5. Both << 1.07e-3.
// MODE 0: bf16 out (Q cols scaled 0.125*log2e). MODE 1: fp32 out.
// ---------------------------------------------------------------------------
template <int MODE>
__global__ __launch_bounds__(256)
void gemm_bf(const ushort* __restrict__ A, const ushort* __restrict__ Bt,
             const float* __restrict__ b0, const float* __restrict__ b1,
             const float* __restrict__ b2, void* __restrict__ Cout,
             int M, int N, int K)
{
    __shared__ __align__(16) ushort Ah[64 * 32];
    __shared__ __align__(16) ushort Bh[128 * 32];

    const int tid = threadIdx.x;
    const int lane = tid & 63, wv = tid >> 6;
    const int wr = wv >> 1, wc = wv & 1;
    const int m = lane & 15, c = lane >> 4;
    const int row0 = blockIdx.y * 64, col0 = blockIdx.x * 128;

    // A staging: 1 slot/thread (64 rows x 32 cols)
    const ushort* gA = A + (size_t)(row0 + (tid >> 2)) * K + (tid & 3) * 8;
    const int ldsA = tid * 8;
    // B staging: 2 slots/thread (128 rows x 32 cols)
    const ushort* gB[2]; int ldsB[2];
#pragma unroll
    for (int it = 0; it < 2; it++) {
        int idx = it * 256 + tid;
        gB[it] = Bt + (size_t)(col0 + (idx >> 2)) * K + (idx & 3) * 8;
        ldsB[it] = idx * 8;
    }

    f32x4 acc[2][4];
#pragma unroll
    for (int t = 0; t < 2; t++)
#pragma unroll
        for (int u = 0; u < 4; u++) acc[t][u] = (f32x4){0.f, 0.f, 0.f, 0.f};

    for (int k0 = 0; k0 < K; k0 += 32) {
        __syncthreads();
        async16(gA + k0, Ah + ldsA);
#pragma unroll
        for (int it = 0; it < 2; it++) async16(gB[it] + k0, Bh + ldsB[it]);
        __syncthreads();

        s16x8 ah[2], bh[4];
#pragma unroll
        for (int t = 0; t < 2; t++)
            ah[t] = *(const s16x8*)&Ah[(wr * 32 + t * 16 + m) * 32 + c * 8];
#pragma unroll
        for (int u = 0; u < 4; u++)
            bh[u] = *(const s16x8*)&Bh[(wc * 64 + u * 16 + m) * 32 + c * 8];
#pragma unroll
        for (int t = 0; t < 2; t++)
#pragma unroll
            for (int u = 0; u < 4; u++)
                acc[t][u] = __builtin_amdgcn_mfma_f32_16x16x32_bf16(ah[t], bh[u], acc[t][u], 0, 0, 0);
    }

    const int orow = row0 + wr * 32 + 4 * c;   // + 16t + r
    const int ocol = col0 + wc * 64 + m;       // + 16u
    if (MODE == 0) {
        ushort* Cb = (ushort*)Cout;
#pragma unroll
        for (int u = 0; u < 4; u++) {
            int n = ocol + 16 * u;
            float bias, scl;
            if (n < 1024)      { bias = b0[n];        scl = 0.18033688f; }  // 0.125*log2(e)
            else if (n < 1280) { bias = b1[n - 1024]; scl = 1.0f; }
            else               { bias = b2[n - 1280]; scl = 1.0f; }
#pragma unroll
            for (int t = 0; t < 2; t++)
#pragma unroll
                for (int r = 0; r < 4; r++)
                    Cb[(size_t)(orow + 16 * t + r) * N + n] = f2bf((acc[t][u][r] + bias) * scl);
        }
    } else {
        float* Cf = (float*)Cout;
#pragma unroll
        for (int u = 0; u < 4; u++) {
            int n = ocol + 16 * u;
            float bias = b0[n];
#pragma unroll
            for (int t = 0; t < 2; t++)
#pragma unroll
                for (int r = 0; r < 4; r++)
                    Cf[(size_t)(orow + 16 * t + r) * N + n] = acc[t][u][r] + bias;
        }
    }
}

// ---------------------------------------------------------------------------
// Pack K and V (bf16 cols of QKV) into fragment-major buffers (unchanged).
// ---------------------------------------------------------------------------
__global__ __launch_bounds__(256)
void kvpack(const ushort* __restrict__ QKV, ushort* __restrict__ Kf,
            ushort* __restrict__ Vf)
{
    __shared__ __align__(16) ushort Kt[64][72];
    __shared__ __align__(16) ushort Vt[64][72];
    const int kt = blockIdx.x, hk = blockIdx.y, b = blockIdx.z;
    const int tid = threadIdx.x;

#pragma unroll
    for (int it = 0; it < 2; it++) {
        int idx = tid + it * 256;
        int r = idx >> 3, c8 = (idx & 7) * 8;
        const ushort* src = QKV + (size_t)(b * SEQ + kt * 64 + r) * NQKV + hk * HDIM + c8;
        *(s16x8*)&Kt[r][c8] = *(const s16x8*)(src + 1024);
        *(s16x8*)&Vt[r][c8] = *(const s16x8*)(src + 1280);
    }
    __syncthreads();

#pragma unroll
    for (int it = 0; it < 2; it++) {
        int idx = tid + it * 256;
        int t32 = idx >> 8, kc = (idx >> 6) & 3, lane = idx & 63;
        int n32 = lane & 31, h5 = lane >> 5;
        s16x8 fr = *(const s16x8*)&Kt[t32 * 32 + n32][kc * 16 + h5 * 8];
        size_t flat = ((size_t)(((b * NKV + hk) * 64 + kt * 2 + t32) * 4 + kc) * 64 + lane) * 8;
        *(s16x8*)(Kf + flat) = fr;
    }
#pragma unroll
    for (int it = 0; it < 2; it++) {
        int idx = tid + it * 256;
        int kcdn = idx >> 6, lane = idx & 63;
        int kc = kcdn >> 1, dn = kcdn & 1;
        int n32 = lane & 31, h5 = lane >> 5;
        s16x8 fr;
#pragma unroll
        for (int j = 0; j < 8; j++)
            fr[j] = (short)Vt[kc * 16 + h5 * 8 + j][dn * 32 + n32];
        size_t flat = ((size_t)(((b * NKV + hk) * 32 + kt) * 8 + kc * 2 + dn) * 64 + lane) * 8;
        *(s16x8*)(Vf + flat) = fr;
    }
}

// ---------------------------------------------------------------------------
// Flash attention v10 = v7 core MINUS the ones-MFMA l-accumulation.
// l[q] = sum_k p[q][k] is now computed as an f32 add-tree on the p values
// already in registers inside QK_EXP_STORE (15 adds per kn, independent of
// the pack ops), cross-h5 combined ONCE after the loop via shfl_xor(32).
// Removes 4 of 20 MFMAs per tile per wave (-20% MFMA work), the serial accl
// chain, and ~20 VGPRs (accl f32x16 + ones). Pure work/register removal —
// the R2/R3 regressions were both register ADDITIONS (80->96); this goes
// the other way. Denominator now uses f32 p (vs bf16 p): zero-mean ~2^-9
// rel perturbation on softmax weights, absmax shift ~1e-5 vs 4x margin.
// ---------------------------------------------------------------------------
__global__ __launch_bounds__(512, 2)
void attn_mfma10(const ushort* __restrict__ QKV, const ushort* __restrict__ Kf,
                 const ushort* __restrict__ Vf, ushort* __restrict__ Chi)
{
    __shared__ __align__(16) ushort Ps[8][32][68];   // 34,816 B; merge bufs alias
    float* OLb = (float*)&Ps[0][0][0];               // [4][32][64] = 32,768 B
    float* LLb = (float*)((char*)&Ps[0][0][0] + 33024);  // [4][32]

    const int tid = threadIdx.x, w = tid >> 6, lane = tid & 63;
    const int g = w >> 2, ws_ = w & 3;               // q-group, kt-split index
    const int n32 = lane & 31, h5 = lane >> 5;
    const int h = blockIdx.y, b = blockIdx.z, hk = h >> 2;
    const int q0 = blockIdx.x * 64 + g * 32;

    // Q B-fragments (4 k-chunks of 16), hoisted
    const ushort* qrow = QKV + (size_t)(b * SEQ + q0 + n32) * NQKV + h * HDIM + h5 * 8;
    s16x8 aq[4];
#pragma unroll
    for (int kc = 0; kc < 4; kc++) aq[kc] = *(const s16x8*)(qrow + kc * 16);

    f32x16 accO[2];
#pragma unroll
    for (int j = 0; j < 16; j++) { accO[0][j] = 0.f; accO[1][j] = 0.f; }
    float lsum = 0.f;   // per-lane partial l[q=n32] over this lane's key slots

    const ushort* kf0 = Kf + (size_t)(b * NKV + hk) * (64 * 4 * 64 * 8) + (size_t)lane * 8;
    const ushort* vf0 = Vf + (size_t)(b * NKV + hk) * (32 * 8 * 64 * 8) + (size_t)lane * 8;

    s16x8 kreg[8], vreg[8];

#define LOAD_K(kt_) do {                                                      \
    _Pragma("unroll")                                                         \
    for (int kn = 0; kn < 2; kn++)                                            \
        _Pragma("unroll")                                                     \
        for (int kc = 0; kc < 4; kc++)                                        \
            kreg[kn * 4 + kc] =                                               \
                *(const s16x8*)(kf0 + (size_t)(((kt_) * 2 + kn) * 4 + kc) * 512); \
} while (0)

#define LOAD_V(kt_) do {                                                      \
    _Pragma("unroll")                                                         \
    for (int kc = 0; kc < 4; kc++)                                            \
        _Pragma("unroll")                                                     \
        for (int dn = 0; dn < 2; dn++)                                        \
            vreg[kc * 2 + dn] =                                               \
                *(const s16x8*)(vf0 + (size_t)((kt_) * 8 + kc * 2 + dn) * 512); \
} while (0)

// S^T = K Q^T: lane owns q=n32; key(reg) = kn*32 + (reg&3) + 8*(reg>>2) + 4*h5.
// exp2 in log2 domain (log2e folded into Q), packed b64 stores.
// l-partials accumulated here in f32 (tree adds, independent of pack ops).
#define QK_EXP_STORE() do {                                                   \
    _Pragma("unroll")                                                         \
    for (int kn = 0; kn < 2; kn++) {                                          \
        f32x16 S;                                                             \
        _Pragma("unroll")                                                     \
        for (int j = 0; j < 16; j++) S[j] = 0.f;                              \
        _Pragma("unroll")                                                     \
        for (int kc = 0; kc < 4; kc++)                                        \
            S = __builtin_amdgcn_mfma_f32_32x32x16_bf16(kreg[kn * 4 + kc],    \
                    aq[kc], S, 0, 0, 0);                                      \
        float p[16];                                                          \
        _Pragma("unroll")                                                     \
        for (int reg = 0; reg < 16; reg++) p[reg] = EXP2F(S[reg]);            \
        {                                                                     \
            float a0 = p[0] + p[1],   a1 = p[2] + p[3];                       \
            float a2 = p[4] + p[5],   a3 = p[6] + p[7];                       \
            float a4 = p[8] + p[9],   a5 = p[10] + p[11];                     \
            float a6 = p[12] + p[13], a7 = p[14] + p[15];                     \
            lsum += ((a0 + a1) + (a2 + a3)) + ((a4 + a5) + (a6 + a7));        \
        }                                                                     \
        _Pragma("unroll")                                                     \
        for (int t = 0; t < 4; t++) {                                         \
            uint2 pk;                                                         \
            pk.x = pack_rh2(p[4 * t + 0], p[4 * t + 1]);                      \
            pk.y = pack_rh2(p[4 * t + 2], p[4 * t + 3]);                      \
            *(uint2*)&Ps[w][n32][kn * 32 + 8 * t + 4 * h5] = pk;              \
        }                                                                     \
    }                                                                         \
} while (0)

#define PV_STEP() do {                                                        \
    s16x8 pa[4];                                                              \
    _Pragma("unroll")                                                         \
    for (int kc = 0; kc < 4; kc++) {                                          \
        s16x4 lo4 = *(const s16x4*)&Ps[w][n32][kc * 16 + h5 * 8];             \
        s16x4 hi4 = *(const s16x4*)&Ps[w][n32][kc * 16 + h5 * 8 + 4];         \
        pa[kc] = __builtin_shufflevector(lo4, hi4, 0, 1, 2, 3, 4, 5, 6, 7);   \
    }                                                                         \
    _Pragma("unroll")                                                         \
    for (int kc = 0; kc < 4; kc++) {                                          \
        _Pragma("unroll")                                                     \
        for (int dn = 0; dn < 2; dn++)                                        \
            accO[dn] = __builtin_amdgcn_mfma_f32_32x32x16_bf16(pa[kc],        \
                           vreg[kc * 2 + dn], accO[dn], 0, 0, 0);             \
    }                                                                         \
} while (0)

    // prologue: first tile's scores
    LOAD_K(ws_);
    QK_EXP_STORE();

    for (int i = 1; i < 8; i++) {
        const int ktc = ws_ + 4 * i;
        LOAD_V(ktc - 4);     // V for previous tile (issued first: partial vm wait)
        LOAD_K(ktc);         // K for current tile
        PV_STEP();           // PV(prev): reads Ps BEFORE the writes below (in-order DS)
        QK_EXP_STORE();      // scores(cur) + overwrite Ps
    }

    // epilogue: last tile's PV
    LOAD_V(ws_ + 28);
    PV_STEP();

#undef LOAD_K
#undef LOAD_V
#undef QK_EXP_STORE
#undef PV_STEP

    // combine the two h5 halves of l[q=n32] (each lane then holds the full sum)
    lsum += __shfl_xor(lsum, 32, 64);

    __syncthreads();   // everyone done with Ps — safe to alias merge buffers

    const int qq = tid >> 4;          // 0..31
    const int d0 = (tid & 15) * 4;    // 0..60
#pragma unroll
    for (int phase = 0; phase < 2; phase++) {
        if (g == phase) {
#pragma unroll
            for (int reg = 0; reg < 16; reg++) {
                int q = (reg & 3) + 8 * (reg >> 2) + 4 * h5;
                OLb[(ws_ * 32 + q) * 64 + n32]      = accO[0][reg];
                OLb[(ws_ * 32 + q) * 64 + 32 + n32] = accO[1][reg];
            }
            if (h5 == 0) LLb[ws_ * 32 + n32] = lsum;
        }
        __syncthreads();
        {
            float lsum2 = LLb[qq] + LLb[32 + qq] + LLb[64 + qq] + LLb[96 + qq];
            float inv = 1.f / lsum2;
            ushort4 hs;
            float o0 = (OLb[(0 * 32 + qq) * 64 + d0 + 0] + OLb[(1 * 32 + qq) * 64 + d0 + 0] +
                        OLb[(2 * 32 + qq) * 64 + d0 + 0] + OLb[(3 * 32 + qq) * 64 + d0 + 0]) * inv;
            float o1 = (OLb[(0 * 32 + qq) * 64 + d0 + 1] + OLb[(1 * 32 + qq) * 64 + d0 + 1] +
                        OLb[(2 * 32 + qq) * 64 + d0 + 1] + OLb[(3 * 32 + qq) * 64 + d0 + 1]) * inv;
            float o2 = (OLb[(0 * 32 + qq) * 64 + d0 + 2] + OLb[(1 * 32 + qq) * 64 + d0 + 2] +
                        OLb[(2 * 32 + qq) * 64 + d0 + 2] + OLb[(3 * 32 + qq) * 64 + d0 + 2]) * inv;
            float o3 = (OLb[(0 * 32 + qq) * 64 + d0 + 3] + OLb[(1 * 32 + qq) * 64 + d0 + 3] +
                        OLb[(2 * 32 + qq) * 64 + d0 + 3] + OLb[(3 * 32 + qq) * 64 + d0 + 3]) * inv;
            hs.x = f2bf(o0); hs.y = f2bf(o1); hs.z = f2bf(o2); hs.w = f2bf(o3);
            size_t off = (size_t)(b * SEQ + blockIdx.x * 64 + phase * 32 + qq) * HIDDEN
                       + h * HDIM + d0;
            *(ushort4*)(Chi + off) = hs;
        }
        __syncthreads();   // before next phase overwrites merge buffers
    }
}

// ---------------------------------------------------------------------------
extern "C" void kernel_launch(void* const* d_in, const int* in_sizes, int n_in,
                              void* d_out, int out_size, void* d_ws, size_t ws_size,
                              hipStream_t stream)
{
    const float* X  = (const float*)d_in[0];
    const float* Wq = (const float*)d_in[1];
    const float* bq = (const float*)d_in[2];
    const float* Wk = (const float*)d_in[3];
    const float* bk = (const float*)d_in[4];
    const float* Wv = (const float*)d_in[5];
    const float* bv = (const float*)d_in[6];
    const float* Wo = (const float*)d_in[7];
    const float* bo = (const float*)d_in[8];
    float* out = (float*)d_out;

    const int M = BATCH * SEQ;  // 4096
    // ws layout (37 MB): Xb 8 | Ctx 8 | QKVb 12 | Wqkvt 3 | Wot 2 | Kf 2 | Vf 2
    char* ws = (char*)d_ws;
    ushort* Xb    = (ushort*)(ws);
    ushort* Ctx   = (ushort*)(ws + (8u  << 20));
    ushort* QKVb  = (ushort*)(ws + (16u << 20));
    ushort* Wqkvt = (ushort*)(ws + (28u << 20));
    ushort* Wot   = (ushort*)(ws + (31u << 20));
    ushort* Kf    = (ushort*)(ws + (33u << 20));
    ushort* Vf    = (ushort*)(ws + (35u << 20));

    prep<<<dim3(4736), 256, 0, stream>>>(X, Xb, Wq, Wk, Wv, Wqkvt, Wo, Wot);

    gemm_bf<0><<<dim3(NQKV / 128, M / 64), 256, 0, stream>>>(
        Xb, Wqkvt, bq, bk, bv, (void*)QKVb, M, NQKV, HIDDEN);

    kvpack<<<dim3(SEQ / 64, NKV, BATCH), 256, 0, stream>>>(QKVb, Kf, Vf);

    attn_mfma10<<<dim3(SEQ / 64, NHEAD, BATCH), 512, 0, stream>>>(QKVb, Kf, Vf, Ctx);

    gemm_bf<1><<<dim3(HIDDEN / 128, M / 64), 256, 0, stream>>>(
        Ctx, Wot, bo, nullptr, nullptr, (void*)out, M, HIDDEN, HIDDEN);
}

// Round 6
// 189.434 us; speedup vs baseline: 1.0601x; 1.0363x over previous
//
#include <hip/hip_runtime.h>
#include <hip/hip_bf16.h>

#define HIDDEN 1024
#define NHEAD 16
#define NKV 4
#define HDIM 64
#define KVDIM 256
#define SEQ 2048
#define BATCH 2
#define NQKV 1536   // 1024 (Q) + 256 (K) + 256 (V)

typedef __attribute__((ext_vector_type(4)))  float f32x4;
typedef __attribute__((ext_vector_type(16))) float f32x16;
typedef __attribute__((ext_vector_type(8)))  short s16x8;
typedef __attribute__((ext_vector_type(4)))  short s16x4;

#if defined(__has_builtin)
#if __has_builtin(__builtin_amdgcn_exp2f)
#define EXP2F(x) __builtin_amdgcn_exp2f(x)
#else
#define EXP2F(x) exp2f(x)
#endif
#else
#define EXP2F(x) exp2f(x)
#endif

static __device__ __forceinline__ ushort f2bf(float f) {
    union { __hip_bfloat16 b; ushort u; } cv; cv.b = __float2bfloat16(f); return cv.u;
}
// pack two positive finite f32 into (lo,hi) bf16 pair, round-half-up
static __device__ __forceinline__ unsigned pack_rh2(float a, float b) {
    unsigned ua = __float_as_uint(a) + 0x8000u;
    unsigned ub = __float_as_uint(b) + 0x8000u;
    return (ua >> 16) | (ub & 0xFFFF0000u);
}
// async global->LDS, 16B per lane. LDS dest = wave-uniform base + lane*16.
static __device__ __forceinline__ void async16(const void* g, void* l) {
    __builtin_amdgcn_global_load_lds((__attribute__((address_space(1))) void*)g,
                                     (__attribute__((address_space(3))) void*)l, 16, 0, 0);
}

// ---------------------------------------------------------------------------
// Fused prep: grid [0,4096) = X fp32->bf16; [4096,4480) = Wq/Wk/Wv transpose;
// [4480,4736) = Wo transpose. One dispatch instead of three.
// ---------------------------------------------------------------------------
__global__ __launch_bounds__(256)
void prep(const float* __restrict__ X, ushort* __restrict__ Xb,
          const float* __restrict__ Wq, const float* __restrict__ Wk,
          const float* __restrict__ Wv, ushort* __restrict__ Tqkv,
          const float* __restrict__ Wo, ushort* __restrict__ Two)
{
    __shared__ float Tl[64][65];
    const int bid = blockIdx.x, tid = threadIdx.x;

    if (bid < 4096) {           // ---- cvt_x: 4096 blocks x 256 thr x float4
        int i = bid * 256 + tid;
        float4 v = ((const float4*)X)[i];
        ushort4 o;
        o.x = f2bf(v.x); o.y = f2bf(v.y); o.z = f2bf(v.z); o.w = f2bf(v.w);
        ((ushort4*)Xb)[i] = o;
        return;
    }

    const float* W; ushort* T; int N, n0, k0, roff;
    if (bid < 4096 + 384) {     // ---- wtrans_qkv (24 x 16)
        int wq = bid - 4096;
        int bx = wq % 24; k0 = (wq / 24) * 64;
        T = Tqkv;
        if (bx < 16)      { W = Wq; N = 1024; n0 = bx * 64;        roff = 0; }
        else if (bx < 20) { W = Wk; N = 256;  n0 = (bx - 16) * 64; roff = 1024; }
        else              { W = Wv; N = 256;  n0 = (bx - 20) * 64; roff = 1280; }
    } else {                    // ---- wtrans_one (Wo, 16 x 16)
        int wo = bid - 4480;
        int bx = wo % 16; k0 = (wo / 16) * 64;
        W = Wo; T = Two; N = 1024; n0 = bx * 64; roff = 0;
    }

#pragma unroll
    for (int it = 0; it < 4; it++) {
        int idx = tid + it * 256;
        int kk = idx >> 4, n4 = (idx & 15) * 4;
        float4 v = *(const float4*)(W + (size_t)(k0 + kk) * N + n0 + n4);
        Tl[kk][n4 + 0] = v.x; Tl[kk][n4 + 1] = v.y;
        Tl[kk][n4 + 2] = v.z; Tl[kk][n4 + 3] = v.w;
    }
    __syncthreads();
#pragma unroll
    for (int it = 0; it < 4; it++) {
        int idx = tid + it * 256;
        int n = idx >> 4, k4 = (idx & 15) * 4;
        ushort4 h4;
        h4.x = f2bf(Tl[k4 + 0][n]); h4.y = f2bf(Tl[k4 + 1][n]);
        h4.z = f2bf(Tl[k4 + 2][n]); h4.w = f2bf(Tl[k4 + 3][n]);
        *(ushort4*)(T + (size_t)(roff + n0 + n) * HIDDEN + k0 + k4) = h4;
    }
}

// ---------------------------------------------------------------------------
// Plain-bf16 MFMA GEMM (R0 geometry — measured best): C = A[M,K]@B^T[N,K]+bias.
// 64x128 tile (M x N), BK=32, 4 waves 2x2; per wave 2x4 grid of 16x16x32.
// Grids: gemm0 (12,64)=768 wgs ~3/CU; gemm1 (8,64)=512 wgs = 2/CU.
// Error analysis: QKV operand-rounding ~2.5e-3 on q~0.64 contracts via
// softmax-averaging to ~7e-5 in ctx; O-proj ~3.5e-5. Both << 1.07e-3.
// MODE 0: bf16 out (Q cols scaled 0.125*log2e). MODE 1: fp32 out.
// ---------------------------------------------------------------------------
template <int MODE>
__global__ __launch_bounds__(256)
void gemm_bf(const ushort* __restrict__ A, const ushort* __restrict__ Bt,
             const float* __restrict__ b0, const float* __restrict__ b1,
             const float* __restrict__ b2, void* __restrict__ Cout,
             int M, int N, int K)
{
    __shared__ __align__(16) ushort Ah[64 * 32];
    __shared__ __align__(16) ushort Bh[128 * 32];

    const int tid = threadIdx.x;
    const int lane = tid & 63, wv = tid >> 6;
    const int wr = wv >> 1, wc = wv & 1;
    const int m = lane & 15, c = lane >> 4;
    const int row0 = blockIdx.y * 64, col0 = blockIdx.x * 128;

    // A staging: 1 slot/thread (64 rows x 32 cols)
    const ushort* gA = A + (size_t)(row0 + (tid >> 2)) * K + (tid & 3) * 8;
    const int ldsA = tid * 8;
    // B staging: 2 slots/thread (128 rows x 32 cols)
    const ushort* gB[2]; int ldsB[2];
#pragma unroll
    for (int it = 0; it < 2; it++) {
        int idx = it * 256 + tid;
        gB[it] = Bt + (size_t)(col0 + (idx >> 2)) * K + (idx & 3) * 8;
        ldsB[it] = idx * 8;
    }

    f32x4 acc[2][4];
#pragma unroll
    for (int t = 0; t < 2; t++)
#pragma unroll
        for (int u = 0; u < 4; u++) acc[t][u] = (f32x4){0.f, 0.f, 0.f, 0.f};

    for (int k0 = 0; k0 < K; k0 += 32) {
        __syncthreads();
        async16(gA + k0, Ah + ldsA);
#pragma unroll
        for (int it = 0; it < 2; it++) async16(gB[it] + k0, Bh + ldsB[it]);
        __syncthreads();

        s16x8 ah[2], bh[4];
#pragma unroll
        for (int t = 0; t < 2; t++)
            ah[t] = *(const s16x8*)&Ah[(wr * 32 + t * 16 + m) * 32 + c * 8];
#pragma unroll
        for (int u = 0; u < 4; u++)
            bh[u] = *(const s16x8*)&Bh[(wc * 64 + u * 16 + m) * 32 + c * 8];
#pragma unroll
        for (int t = 0; t < 2; t++)
#pragma unroll
            for (int u = 0; u < 4; u++)
                acc[t][u] = __builtin_amdgcn_mfma_f32_16x16x32_bf16(ah[t], bh[u], acc[t][u], 0, 0, 0);
    }

    const int orow = row0 + wr * 32 + 4 * c;   // + 16t + r
    const int ocol = col0 + wc * 64 + m;       // + 16u
    if (MODE == 0) {
        ushort* Cb = (ushort*)Cout;
#pragma unroll
        for (int u = 0; u < 4; u++) {
            int n = ocol + 16 * u;
            float bias, scl;
            if (n < 1024)      { bias = b0[n];        scl = 0.18033688f; }  // 0.125*log2(e)
            else if (n < 1280) { bias = b1[n - 1024]; scl = 1.0f; }
            else               { bias = b2[n - 1280]; scl = 1.0f; }
#pragma unroll
            for (int t = 0; t < 2; t++)
#pragma unroll
                for (int r = 0; r < 4; r++)
                    Cb[(size_t)(orow + 16 * t + r) * N + n] = f2bf((acc[t][u][r] + bias) * scl);
        }
    } else {
        float* Cf = (float*)Cout;
#pragma unroll
        for (int u = 0; u < 4; u++) {
            int n = ocol + 16 * u;
            float bias = b0[n];
#pragma unroll
            for (int t = 0; t < 2; t++)
#pragma unroll
                for (int r = 0; r < 4; r++)
                    Cf[(size_t)(orow + 16 * t + r) * N + n] = acc[t][u][r] + bias;
        }
    }
}

// ---------------------------------------------------------------------------
// Pack K and V (bf16 cols of QKV) into fragment-major buffers (unchanged).
// ---------------------------------------------------------------------------
__global__ __launch_bounds__(256)
void kvpack(const ushort* __restrict__ QKV, ushort* __restrict__ Kf,
            ushort* __restrict__ Vf)
{
    __shared__ __align__(16) ushort Kt[64][72];
    __shared__ __align__(16) ushort Vt[64][72];
    const int kt = blockIdx.x, hk = blockIdx.y, b = blockIdx.z;
    const int tid = threadIdx.x;

#pragma unroll
    for (int it = 0; it < 2; it++) {
        int idx = tid + it * 256;
        int r = idx >> 3, c8 = (idx & 7) * 8;
        const ushort* src = QKV + (size_t)(b * SEQ + kt * 64 + r) * NQKV + hk * HDIM + c8;
        *(s16x8*)&Kt[r][c8] = *(const s16x8*)(src + 1024);
        *(s16x8*)&Vt[r][c8] = *(const s16x8*)(src + 1280);
    }
    __syncthreads();

#pragma unroll
    for (int it = 0; it < 2; it++) {
        int idx = tid + it * 256;
        int t32 = idx >> 8, kc = (idx >> 6) & 3, lane = idx & 63;
        int n32 = lane & 31, h5 = lane >> 5;
        s16x8 fr = *(const s16x8*)&Kt[t32 * 32 + n32][kc * 16 + h5 * 8];
        size_t flat = ((size_t)(((b * NKV + hk) * 64 + kt * 2 + t32) * 4 + kc) * 64 + lane) * 8;
        *(s16x8*)(Kf + flat) = fr;
    }
#pragma unroll
    for (int it = 0; it < 2; it++) {
        int idx = tid + it * 256;
        int kcdn = idx >> 6, lane = idx & 63;
        int kc = kcdn >> 1, dn = kcdn & 1;
        int n32 = lane & 31, h5 = lane >> 5;
        s16x8 fr;
#pragma unroll
        for (int j = 0; j < 8; j++)
            fr[j] = (short)Vt[kc * 16 + h5 * 8 + j][dn * 32 + n32];
        size_t flat = ((size_t)(((b * NKV + hk) * 32 + kt) * 8 + kc * 2 + dn) * 64 + lane) * 8;
        *(s16x8*)(Vf + flat) = fr;
    }
}

// ---------------------------------------------------------------------------
// Flash attention v11 = v10 (f32-tree lsum, no ones-MFMA) + rotated load
// schedule. v10's per-tile stall: LOAD_V(prev) was consumed by PV in the
// SAME iteration (~zero cover); LOAD_K(cur) consumed same iteration too.
// Rotation: each load is issued immediately AFTER the consumer of its
// register bank, giving every load a full compute phase of cover, and the
// in-order vmcnt counter always waits on the OLDEST loads (vmcnt(8)),
// never draining the newer prefetch. Zero new registers (single kreg/vreg
// banks preserved — R3's dbuf failure mode was +16 VGPR, avoided here).
// DS ordering unchanged: QK(i-1) writes Ps before PV(i) reads it; PV(i)
// reads before QK(i) overwrites. Arithmetic identical to v10.
// ---------------------------------------------------------------------------
__global__ __launch_bounds__(512, 2)
void attn_mfma11(const ushort* __restrict__ QKV, const ushort* __restrict__ Kf,
                 const ushort* __restrict__ Vf, ushort* __restrict__ Chi)
{
    __shared__ __align__(16) ushort Ps[8][32][68];   // 34,816 B; merge bufs alias
    float* OLb = (float*)&Ps[0][0][0];               // [4][32][64] = 32,768 B
    float* LLb = (float*)((char*)&Ps[0][0][0] + 33024);  // [4][32]

    const int tid = threadIdx.x, w = tid >> 6, lane = tid & 63;
    const int g = w >> 2, ws_ = w & 3;               // q-group, kt-split index
    const int n32 = lane & 31, h5 = lane >> 5;
    const int h = blockIdx.y, b = blockIdx.z, hk = h >> 2;
    const int q0 = blockIdx.x * 64 + g * 32;

    // Q B-fragments (4 k-chunks of 16), hoisted
    const ushort* qrow = QKV + (size_t)(b * SEQ + q0 + n32) * NQKV + h * HDIM + h5 * 8;
    s16x8 aq[4];
#pragma unroll
    for (int kc = 0; kc < 4; kc++) aq[kc] = *(const s16x8*)(qrow + kc * 16);

    f32x16 accO[2];
#pragma unroll
    for (int j = 0; j < 16; j++) { accO[0][j] = 0.f; accO[1][j] = 0.f; }
    float lsum = 0.f;   // per-lane partial l[q=n32] over this lane's key slots

    const ushort* kf0 = Kf + (size_t)(b * NKV + hk) * (64 * 4 * 64 * 8) + (size_t)lane * 8;
    const ushort* vf0 = Vf + (size_t)(b * NKV + hk) * (32 * 8 * 64 * 8) + (size_t)lane * 8;

    s16x8 kreg[8], vreg[8];

#define LOAD_K(kt_) do {                                                      \
    _Pragma("unroll")                                                         \
    for (int kn = 0; kn < 2; kn++)                                            \
        _Pragma("unroll")                                                     \
        for (int kc = 0; kc < 4; kc++)                                        \
            kreg[kn * 4 + kc] =                                               \
                *(const s16x8*)(kf0 + (size_t)(((kt_) * 2 + kn) * 4 + kc) * 512); \
} while (0)

#define LOAD_V(kt_) do {                                                      \
    _Pragma("unroll")                                                         \
    for (int kc = 0; kc < 4; kc++)                                            \
        _Pragma("unroll")                                                     \
        for (int dn = 0; dn < 2; dn++)                                        \
            vreg[kc * 2 + dn] =                                               \
                *(const s16x8*)(vf0 + (size_t)((kt_) * 8 + kc * 2 + dn) * 512); \
} while (0)

// S^T = K Q^T: lane owns q=n32; key(reg) = kn*32 + (reg&3) + 8*(reg>>2) + 4*h5.
// exp2 in log2 domain (log2e folded into Q), packed b64 stores.
// l-partials accumulated here in f32 (tree adds, independent of pack ops).
#define QK_EXP_STORE() do {                                                   \
    _Pragma("unroll")                                                         \
    for (int kn = 0; kn < 2; kn++) {                                          \
        f32x16 S;                                                             \
        _Pragma("unroll")                                                     \
        for (int j = 0; j < 16; j++) S[j] = 0.f;                              \
        _Pragma("unroll")                                                     \
        for (int kc = 0; kc < 4; kc++)                                        \
            S = __builtin_amdgcn_mfma_f32_32x32x16_bf16(kreg[kn * 4 + kc],    \
                    aq[kc], S, 0, 0, 0);                                      \
        float p[16];                                                          \
        _Pragma("unroll")                                                     \
        for (int reg = 0; reg < 16; reg++) p[reg] = EXP2F(S[reg]);            \
        {                                                                     \
            float a0 = p[0] + p[1],   a1 = p[2] + p[3];                       \
            float a2 = p[4] + p[5],   a3 = p[6] + p[7];                       \
            float a4 = p[8] + p[9],   a5 = p[10] + p[11];                     \
            float a6 = p[12] + p[13], a7 = p[14] + p[15];                     \
            lsum += ((a0 + a1) + (a2 + a3)) + ((a4 + a5) + (a6 + a7));        \
        }                                                                     \
        _Pragma("unroll")                                                     \
        for (int t = 0; t < 4; t++) {                                         \
            uint2 pk;                                                         \
            pk.x = pack_rh2(p[4 * t + 0], p[4 * t + 1]);                      \
            pk.y = pack_rh2(p[4 * t + 2], p[4 * t + 3]);                      \
            *(uint2*)&Ps[w][n32][kn * 32 + 8 * t + 4 * h5] = pk;              \
        }                                                                     \
    }                                                                         \
} while (0)

#define PV_STEP() do {                                                        \
    s16x8 pa[4];                                                              \
    _Pragma("unroll")                                                         \
    for (int kc = 0; kc < 4; kc++) {                                          \
        s16x4 lo4 = *(const s16x4*)&Ps[w][n32][kc * 16 + h5 * 8];             \
        s16x4 hi4 = *(const s16x4*)&Ps[w][n32][kc * 16 + h5 * 8 + 4];         \
        pa[kc] = __builtin_shufflevector(lo4, hi4, 0, 1, 2, 3, 4, 5, 6, 7);   \
    }                                                                         \
    _Pragma("unroll")                                                         \
    for (int kc = 0; kc < 4; kc++) {                                          \
        _Pragma("unroll")                                                     \
        for (int dn = 0; dn < 2; dn++)                                        \
            accO[dn] = __builtin_amdgcn_mfma_f32_32x32x16_bf16(pa[kc],        \
                           vreg[kc * 2 + dn], accO[dn], 0, 0, 0);             \
    }                                                                         \
} while (0)

    // prologue: K0+V0 in flight; QK(t0) waits only K0 (V0 stays outstanding);
    // K1 issued right after QK consumed kreg.
    LOAD_K(ws_);
    LOAD_V(ws_);
    QK_EXP_STORE();
    LOAD_K(ws_ + 4);

#pragma unroll
    for (int i = 1; i < 8; i++) {
        PV_STEP();               // waits V_{i-1} (oldest); K_i stays in flight
        LOAD_V(ws_ + 4 * i);     // V_i: cover = QK(i)+exp below
        QK_EXP_STORE();          // waits K_i (oldest); V_i stays in flight
        if (i < 7) LOAD_K(ws_ + 4 * (i + 1));   // K_{i+1}: cover = PV(i)
    }
    // epilogue: last tile's PV
    PV_STEP();

#undef LOAD_K
#undef LOAD_V
#undef QK_EXP_STORE
#undef PV_STEP

    // combine the two h5 halves of l[q=n32] (each lane then holds the full sum)
    lsum += __shfl_xor(lsum, 32, 64);

    __syncthreads();   // everyone done with Ps — safe to alias merge buffers

    const int qq = tid >> 4;          // 0..31
    const int d0 = (tid & 15) * 4;    // 0..60
#pragma unroll
    for (int phase = 0; phase < 2; phase++) {
        if (g == phase) {
#pragma unroll
            for (int reg = 0; reg < 16; reg++) {
                int q = (reg & 3) + 8 * (reg >> 2) + 4 * h5;
                OLb[(ws_ * 32 + q) * 64 + n32]      = accO[0][reg];
                OLb[(ws_ * 32 + q) * 64 + 32 + n32] = accO[1][reg];
            }
            if (h5 == 0) LLb[ws_ * 32 + n32] = lsum;
        }
        __syncthreads();
        {
            float lsum2 = LLb[qq] + LLb[32 + qq] + LLb[64 + qq] + LLb[96 + qq];
            float inv = 1.f / lsum2;
            ushort4 hs;
            float o0 = (OLb[(0 * 32 + qq) * 64 + d0 + 0] + OLb[(1 * 32 + qq) * 64 + d0 + 0] +
                        OLb[(2 * 32 + qq) * 64 + d0 + 0] + OLb[(3 * 32 + qq) * 64 + d0 + 0]) * inv;
            float o1 = (OLb[(0 * 32 + qq) * 64 + d0 + 1] + OLb[(1 * 32 + qq) * 64 + d0 + 1] +
                        OLb[(2 * 32 + qq) * 64 + d0 + 1] + OLb[(3 * 32 + qq) * 64 + d0 + 1]) * inv;
            float o2 = (OLb[(0 * 32 + qq) * 64 + d0 + 2] + OLb[(1 * 32 + qq) * 64 + d0 + 2] +
                        OLb[(2 * 32 + qq) * 64 + d0 + 2] + OLb[(3 * 32 + qq) * 64 + d0 + 2]) * inv;
            float o3 = (OLb[(0 * 32 + qq) * 64 + d0 + 3] + OLb[(1 * 32 + qq) * 64 + d0 + 3] +
                        OLb[(2 * 32 + qq) * 64 + d0 + 3] + OLb[(3 * 32 + qq) * 64 + d0 + 3]) * inv;
            hs.x = f2bf(o0); hs.y = f2bf(o1); hs.z = f2bf(o2); hs.w = f2bf(o3);
            size_t off = (size_t)(b * SEQ + blockIdx.x * 64 + phase * 32 + qq) * HIDDEN
                       + h * HDIM + d0;
            *(ushort4*)(Chi + off) = hs;
        }
        __syncthreads();   // before next phase overwrites merge buffers
    }
}

// ---------------------------------------------------------------------------
extern "C" void kernel_launch(void* const* d_in, const int* in_sizes, int n_in,
                              void* d_out, int out_size, void* d_ws, size_t ws_size,
                              hipStream_t stream)
{
    const float* X  = (const float*)d_in[0];
    const float* Wq = (const float*)d_in[1];
    const float* bq = (const float*)d_in[2];
    const float* Wk = (const float*)d_in[3];
    const float* bk = (const float*)d_in[4];
    const float* Wv = (const float*)d_in[5];
    const float* bv = (const float*)d_in[6];
    const float* Wo = (const float*)d_in[7];
    const float* bo = (const float*)d_in[8];
    float* out = (float*)d_out;

    const int M = BATCH * SEQ;  // 4096
    // ws layout (37 MB): Xb 8 | Ctx 8 | QKVb 12 | Wqkvt 3 | Wot 2 | Kf 2 | Vf 2
    char* ws = (char*)d_ws;
    ushort* Xb    = (ushort*)(ws);
    ushort* Ctx   = (ushort*)(ws + (8u  << 20));
    ushort* QKVb  = (ushort*)(ws + (16u << 20));
    ushort* Wqkvt = (ushort*)(ws + (28u << 20));
    ushort* Wot   = (ushort*)(ws + (31u << 20));
    ushort* Kf    = (ushort*)(ws + (33u << 20));
    ushort* Vf    = (ushort*)(ws + (35u << 20));

    prep<<<dim3(4736), 256, 0, stream>>>(X, Xb, Wq, Wk, Wv, Wqkvt, Wo, Wot);

    gemm_bf<0><<<dim3(NQKV / 128, M / 64), 256, 0, stream>>>(
        Xb, Wqkvt, bq, bk, bv, (void*)QKVb, M, NQKV, HIDDEN);

    kvpack<<<dim3(SEQ / 64, NKV, BATCH), 256, 0, stream>>>(QKVb, Kf, Vf);

    attn_mfma11<<<dim3(SEQ / 64, NHEAD, BATCH), 512, 0, stream>>>(QKVb, Kf, Vf, Ctx);

    gemm_bf<1><<<dim3(HIDDEN / 128, M / 64), 256, 0, stream>>>(
        Ctx, Wot, bo, nullptr, nullptr, (void*)out, M, HIDDEN, HIDDEN);
}